// Round 19
// baseline (248.294 us; speedup 1.0000x reference)
//
#include <hip/hip_runtime.h>
#include <cstdint>
#include <cstddef>

typedef __attribute__((ext_vector_type(8))) short short8;     // 8 x 16-bit (4 VGPRs)
typedef __attribute__((ext_vector_type(8))) _Float16 f16x8;   // fp16 MFMA frag
typedef __attribute__((ext_vector_type(4))) float f32x4;
typedef __attribute__((ext_vector_type(4))) unsigned short u16x4;
typedef unsigned short u16;

#define FP_  2048
#define AD_  1024
#define BB_  512
#define TT_  50000
#define BETA_ 0.125f

// ---------- fp32 -> bf16 (RNE) helpers ----------
__device__ __forceinline__ u16 f2bf(float x){
  uint32_t u = __builtin_bit_cast(uint32_t, x);
  u = (u + 0x7fffu + ((u >> 16) & 1u)) >> 16;
  return (u16)u;
}
__device__ __forceinline__ u16 f2h_bits(float x){
  _Float16 h = (_Float16)x;            // RNE
  return __builtin_bit_cast(u16, h);
}
__device__ __forceinline__ unsigned int pkrtz_u32(float a, float b){
  return __builtin_bit_cast(unsigned int, __builtin_amdgcn_cvt_pkrtz(a, b));
}

// ---------- async global->LDS, 16B per lane ----------
__device__ __forceinline__ void gload_lds16(const void* g, void* l){
  __builtin_amdgcn_global_load_lds((const __attribute__((address_space(1))) void*)g,
                                   (__attribute__((address_space(3))) void*)l,
                                   16, 0, 0);
}

#define SB   __builtin_amdgcn_s_barrier()
#define SCH  __builtin_amdgcn_sched_barrier(0)
#define WAIT_LGKM0 asm volatile("s_waitcnt lgkmcnt(0)" ::: "memory")
#define WAIT_VM(n) asm volatile("s_waitcnt vmcnt(" #n ")" ::: "memory")

// ---------- elementwise fp32 -> bf16 (single) ----------
__global__ void conv_bf_k(const float* __restrict__ src, u16* __restrict__ dst, int n){
  int i = (blockIdx.x * blockDim.x + threadIdx.x) * 4;
  if (i >= n) return;
  f32x4 v = *reinterpret_cast<const f32x4*>(src + i);
  u16x4 h;
  #pragma unroll
  for (int e = 0; e < 4; ++e) h[e] = f2bf(v[e]);
  *reinterpret_cast<u16x4*>(dst + i) = h;
}

// ---------- W[R][C] -> out[C][R] bf16 single (LDS tile transpose) ----------
__global__ void conv_bf_T_k(const float* __restrict__ W, u16* __restrict__ outT,
                            int R, int C){
  __shared__ float tile[32][33];
  int c0 = blockIdx.x * 32;
  int r0 = blockIdx.y * 32;
  int tx = threadIdx.x;   // 0..31
  int ty = threadIdx.y;   // 0..7
  #pragma unroll
  for (int i = 0; i < 32; i += 8)
    tile[ty + i][tx] = W[(size_t)(r0 + ty + i) * C + c0 + tx];
  __syncthreads();
  #pragma unroll
  for (int i = 0; i < 32; i += 8){
    float x = tile[tx][ty + i];              // = W[r0+tx][c0+ty+i]
    outT[(size_t)(c0 + ty + i) * R + r0 + tx] = f2bf(x);
  }
}

// ---------- c[b] = dot(Xi[b,:], b_temp) : one wave per row ----------
__global__ void dot_rows_k(const float* __restrict__ Xi, const float* __restrict__ bt,
                           float* __restrict__ c, int K){
  int row  = blockIdx.x * 4 + (threadIdx.x >> 6);
  int lane = threadIdx.x & 63;
  float s = 0.f;
  for (int a = lane; a < K; a += 64) s += Xi[(size_t)row * K + a] * bt[a];
  #pragma unroll
  for (int off = 32; off; off >>= 1) s += __shfl_down(s, off);
  if (lane == 0) c[row] = s;
}

// ---------- single-bf16 small GEMM: C = A·B^T + colBias ----------
// OUT: 1 = fp32 + bf16 (Xi), 2 = fp16 bits (Y)
template<int TM, int TN, int FM, int FN, int OUT>
__global__ __launch_bounds__(256, 2)
void gemm_s(const u16* __restrict__ A, const u16* __restrict__ B,
            int M, int N, int K,
            float* __restrict__ Cf, u16* __restrict__ C16,
            const float* __restrict__ colBias)
{
  constexpr int BK = 32;
  constexpr int WM = TM / (16 * FM);
  constexpr int WN = TN / (16 * FN);
  static_assert(WM * WN == 4, "4 waves / 256 threads");
  constexpr int BUFE = (TM + TN) * BK;

  __shared__ __align__(16) u16 lds[2 * BUFE];

  const int m0 = blockIdx.x * TM;
  const int n0 = blockIdx.y * TN;

  const int tid  = threadIdx.x;
  const int w    = tid >> 6;
  const int lane = tid & 63;
  const int lr   = lane & 15;
  const int lg   = lane >> 4;
  const int wm   = w / WN;
  const int wn   = w % WN;

  const int rrA = tid >> 2;     // 0..63
  const int chA = tid & 3;      // 16B chunk

  short8 ra, rb;

  f32x4 acc[FM][FN];
  #pragma unroll
  for (int i = 0; i < FM; ++i)
    #pragma unroll
    for (int j = 0; j < FN; ++j)
      acc[i][j] = (f32x4){0.f, 0.f, 0.f, 0.f};

  auto stage_load = [&](int k0){
    int gm = m0 + rrA;
    ra = *reinterpret_cast<const short8*>(A + (size_t)gm * K + k0 + chA * 8);
    int gn = n0 + rrA; if (gn > N - 1) gn = N - 1;
    rb = *reinterpret_cast<const short8*>(B + (size_t)gn * K + k0 + chA * 8);
  };
  auto stage_store = [&](int buf){
    u16* As = lds + buf * BUFE;
    u16* Bs = As + TM * BK;
    int row = rrA;
    int sw  = (chA ^ ((row >> 1) & 3)) << 3;
    *reinterpret_cast<short8*>(As + row * BK + sw) = ra;
    *reinterpret_cast<short8*>(Bs + row * BK + sw) = rb;
  };

  const int NT = K / BK;
  stage_load(0);
  stage_store(0);
  __syncthreads();

  int cur = 0;
  for (int t = 0; t < NT; ++t){
    const bool have_next = (t + 1 < NT);
    if (have_next) stage_load((t + 1) * BK);

    u16* As = lds + cur * BUFE;
    u16* Bs = As + TM * BK;

    short8 ah[FM], bh[FN];
    #pragma unroll
    for (int i = 0; i < FM; ++i){
      int row = wm * FM * 16 + i * 16 + lr;
      int off = row * BK + ((lg ^ ((row >> 1) & 3)) << 3);
      ah[i] = *reinterpret_cast<short8*>(As + off);
    }
    #pragma unroll
    for (int j = 0; j < FN; ++j){
      int row = wn * FN * 16 + j * 16 + lr;
      int off = row * BK + ((lg ^ ((row >> 1) & 3)) << 3);
      bh[j] = *reinterpret_cast<short8*>(Bs + off);
    }
    #pragma unroll
    for (int i = 0; i < FM; ++i)
      #pragma unroll
      for (int j = 0; j < FN; ++j)
        acc[i][j] = __builtin_amdgcn_mfma_f32_16x16x32_bf16(ah[i], bh[j], acc[i][j], 0, 0, 0);

    if (have_next){
      __builtin_amdgcn_sched_barrier(0);
      stage_store(cur ^ 1);
      __syncthreads();
    }
    cur ^= 1;
  }

  #pragma unroll
  for (int i = 0; i < FM; ++i){
    int rbase = m0 + wm * FM * 16 + i * 16 + lg * 4;
    #pragma unroll
    for (int j = 0; j < FN; ++j){
      int gcol = n0 + wn * FN * 16 + j * 16 + lr;
      if (gcol < N){
        float cb = colBias ? colBias[gcol] : 0.f;
        #pragma unroll
        for (int r = 0; r < 4; ++r){
          int grow = rbase + r;
          float v = acc[i][j][r] + cb;
          size_t idx = (size_t)grow * N + gcol;
          if constexpr (OUT == 1){
            Cf[idx]  = v;
            C16[idx] = f2bf(v);
          } else {
            C16[idx] = f2h_bits(v);
          }
        }
      }
    }
  }
}

// ---------- BIG GEMM: 256x256 Gray-code, de-locked (R16), strips 0..127 ----------
// 256 blocks = EXACTLY one per CU -> one round, zero tail quantization.
__global__ __launch_bounds__(512, 1)
void gemm_big(const u16* __restrict__ Ah,      // fp16 bits [512][2048]
              const float* __restrict__ Bf,    // [50000][2048]
              float* __restrict__ C,
              const float* __restrict__ rowAdd, float alpha)
{
  constexpr int K = FP_, NN = TT_;
  constexpr int NT = K / 64;                  // 32 K-tiles
  constexpr int KS = 8192;                    // u16 per ksub block (256x32)
  constexpr int BOFF = 16384;                 // B region offset (u16)
  constexpr int SLOT = 32768;                 // u16 per slot (64KB)

  __shared__ __align__(16) u16 lds[2 * SLOT]; // 128KB

  // strips 0..127: 8 XCD x 16 (mt x 8 strip-slots each... g=0..31: mt,sg)
  int id  = blockIdx.x;
  int xcd = id & 7;
  int g   = id >> 3;          // 0..31
  int mt  = g & 1;            // 2 M-tiles of 256
  int sg  = g >> 1;           // 0..15
  int nt  = xcd * 16 + sg;    // 0..127 bijective
  const int m0 = mt * 256;
  const int n0 = nt * 256;

  const int tid  = threadIdx.x;     // 0..511
  const int w    = tid >> 6;        // 0..7
  const int lane = tid & 63;
  const int lr   = lane & 15;
  const int lg   = lane >> 4;
  const int wm   = w >> 2;          // 0..1 (128-row band)
  const int wn   = w & 3;           // 0..3 (64-col band)

  auto glA = [&](u16* sp_, int Tt, int h){
    int rl = lane >> 2;             // 0..15
    int cc = lane & 3;              // 16B chunk of 64B row
    int row = h * 128 + w * 16 + rl;
    #pragma unroll
    for (int ks = 0; ks < 2; ++ks){
      const u16* src = Ah + (size_t)(m0 + row) * K + Tt * 64 + ks * 32
                     + ((cc ^ ((row >> 1) & 3)) << 3);
      gload_lds16(src, sp_ + ks * KS + (size_t)(h * 128 + w * 16) * 32);
    }
  };
  auto issueB = [&](int Tt, int h, f32x4 (&rb)[4]){
    #pragma unroll
    for (int p = 0; p < 4; ++p){
      int rl = h * 128 + p * 32 + (tid >> 4);
      int gn = n0 + rl; if (gn > NN - 1) gn = NN - 1;
      rb[p] = *reinterpret_cast<const f32x4*>(Bf + (size_t)gn * K + Tt * 64 + (tid & 15) * 4);
    }
  };
  auto publishB = [&](u16* sp_, int h, f32x4 (&rb)[4]){
    int fch = tid & 15;
    int ks  = fch >> 3;
    int c16 = (fch & 7) >> 1;
    int hf  = fch & 1;
    #pragma unroll
    for (int p = 0; p < 4; ++p){
      int row = h * 128 + p * 32 + (tid >> 4);
      uint2 hv;
      hv.x = pkrtz_u32(rb[p][0], rb[p][1]);
      hv.y = pkrtz_u32(rb[p][2], rb[p][3]);
      int phys = c16 ^ ((row >> 1) & 3);
      *reinterpret_cast<uint2*>(sp_ + BOFF + ks * KS + row * 32 + phys * 8 + hf * 4) = hv;
    }
  };

  f32x4 acc[8][4];
  #pragma unroll
  for (int i = 0; i < 8; ++i)
    #pragma unroll
    for (int j = 0; j < 4; ++j)
      acc[i][j] = (f32x4){0.f, 0.f, 0.f, 0.f};

  f32x4 rbB0[4], rbB1[4];
  f16x8 pa[4][2], pb[2][2];

#define READ_PA(SP, MH)                                                        \
  _Pragma("unroll")                                                            \
  for (int ii = 0; ii < 4; ++ii){                                              \
    int row_ = wm * 128 + ((MH) * 4 + ii) * 16 + lr;                           \
    _Pragma("unroll")                                                          \
    for (int ks_ = 0; ks_ < 2; ++ks_)                                          \
      pa[ii][ks_] = __builtin_bit_cast(f16x8, *reinterpret_cast<short8*>(      \
        (SP) + ks_ * KS + row_ * 32 + ((lg ^ ((row_ >> 1) & 3)) << 3)));       \
  }

#define READ_PB(SP, NH)                                                        \
  _Pragma("unroll")                                                            \
  for (int jj = 0; jj < 2; ++jj){                                              \
    int row_ = wn * 64 + ((NH) * 2 + jj) * 16 + lr;                            \
    _Pragma("unroll")                                                          \
    for (int ks_ = 0; ks_ < 2; ++ks_)                                          \
      pb[jj][ks_] = __builtin_bit_cast(f16x8, *reinterpret_cast<short8*>(      \
        (SP) + BOFF + ks_ * KS + row_ * 32 + ((lg ^ ((row_ >> 1) & 3)) << 3)));\
  }

#define MMA(MH, NH)                                                            \
  __builtin_amdgcn_s_setprio(1);                                               \
  _Pragma("unroll")                                                            \
  for (int ii = 0; ii < 4; ++ii)                                               \
    _Pragma("unroll")                                                          \
    for (int jj = 0; jj < 2; ++jj){                                            \
      acc[(MH)*4+ii][(NH)*2+jj] = __builtin_amdgcn_mfma_f32_16x16x32_f16(      \
          pa[ii][0], pb[jj][0], acc[(MH)*4+ii][(NH)*2+jj], 0, 0, 0);           \
      acc[(MH)*4+ii][(NH)*2+jj] = __builtin_amdgcn_mfma_f32_16x16x32_f16(      \
          pa[ii][1], pb[jj][1], acc[(MH)*4+ii][(NH)*2+jj], 0, 0, 0);           \
    }                                                                          \
  __builtin_amdgcn_s_setprio(0);

  glA(lds, 0, 0);  glA(lds, 0, 1);
  SCH;
  issueB(0, 0, rbB0);
  issueB(0, 1, rbB1);
  SCH;
  WAIT_VM(4); SCH;
  publishB(lds, 0, rbB0);
  WAIT_VM(0); SCH;
  publishB(lds, 1, rbB1);
  SCH;
  issueB(1, 0, rbB0);
  issueB(1, 1, rbB1);
  WAIT_LGKM0;
  SB; SCH;

  for (int T = 0; T < NT; ++T){
    u16* sp  = lds + (size_t)(T & 1) * SLOT;
    u16* spn = lds + (size_t)((T + 1) & 1) * SLOT;
    const bool hasN  = (T + 1 < NT);
    const bool hasNN = (T + 2 < NT);

    READ_PA(sp, 0);
    READ_PB(sp, 0);
    if (hasN) glA(spn, T + 1, 0);
    WAIT_LGKM0; SCH;
    MMA(0, 0);

    READ_PB(sp, 1);
    if (hasN){
      glA(spn, T + 1, 1);
      SCH;
      WAIT_VM(8); SCH;
      publishB(spn, 0, rbB0);
      if (hasNN){ issueB(T + 2, 0, rbB0); SCH; }
    }
    WAIT_LGKM0; SCH;
    MMA(0, 1);

    READ_PA(sp, 1);
    if (hasN){
      if (hasNN) { WAIT_VM(8); } else { WAIT_VM(4); }
      SCH;
      publishB(spn, 1, rbB1);
      if (hasNN){ issueB(T + 2, 1, rbB1); SCH; }
    }
    WAIT_LGKM0; SCH;
    MMA(1, 1);

    READ_PB(sp, 0);
    if (hasN){
      if (hasNN) { WAIT_VM(8); } else { WAIT_VM(0); }
      SCH;
    }
    WAIT_LGKM0; SCH;
    MMA(1, 0);
    SCH;
    SB;
  }

#undef READ_PA
#undef READ_PB
#undef MMA

  #pragma unroll
  for (int i = 0; i < 8; ++i){
    int rbase = m0 + wm * 128 + i * 16 + lg * 4;
    #pragma unroll
    for (int j = 0; j < 4; ++j){
      int gcol = n0 + wn * 64 + j * 16 + lr;
      if (gcol < NN){
        #pragma unroll
        for (int r = 0; r < 4; ++r){
          int grow = rbase + r;
          float v = (acc[i][j][r] + rowAdd[grow]) * alpha;
          C[(size_t)grow * NN + gcol] = v;
        }
      }
    }
  }
}

// ---------- QUARTER GEMM: 128x128, BK=64, strips 128..195, 2 blocks/CU ----------
// Geometry-halved clone of gemm_big (same Gray phases, same ledger VM numbers:
// glA call = 2 vmcnt entries, issueB = 4). 256 thr = 4 waves (2Mx2N),
// wave tile 64x64, acc 4x4. LDS 2 x 32KB = 64KB -> 2 blocks/CU.
__global__ __launch_bounds__(256, 2)
void gemm_q(const u16* __restrict__ Ah,
            const float* __restrict__ Bf,
            float* __restrict__ C,
            const float* __restrict__ rowAdd, float alpha)
{
  constexpr int K = FP_, NN = TT_;
  constexpr int NT = K / 64;                  // 32 K-tiles
  constexpr int KS = 4096;                    // u16 per ksub block (128x32)
  constexpr int BOFF = 8192;                  // B region offset (u16)
  constexpr int SLOT = 16384;                 // u16 per slot (32KB)

  __shared__ __align__(16) u16 lds[2 * SLOT]; // 64KB

  // 544 jobs = 68 strips x (4 mq x 2 nh). XCD-chunked bijection:
  // job = (id&7)*68 + (id>>3); strip-consecutive jobs share an XCD (B L2 reuse).
  int id   = blockIdx.x;
  int jobg = (id & 7) * 68 + (id >> 3);       // 0..543
  int strip = jobg >> 3;                      // 0..67
  int sub   = jobg & 7;
  int mq    = sub >> 1;                       // 0..3 (M-tiles of 128)
  int nh    = sub & 1;                        // 0..1 (N-halves of 128)
  const int m0 = mq * 128;
  const int n0 = (128 + strip) * 256 + nh * 128;

  const int tid  = threadIdx.x;     // 0..255
  const int w    = tid >> 6;        // 0..3
  const int lane = tid & 63;
  const int lr   = lane & 15;
  const int lg   = lane >> 4;
  const int wm   = w >> 1;          // 0..1 (64-row band)
  const int wn   = w & 1;           // 0..1 (64-col band)

  auto glA = [&](u16* sp_, int Tt, int h){
    int rl = lane >> 2;             // 0..15
    int cc = lane & 3;
    int row = h * 64 + w * 16 + rl;
    #pragma unroll
    for (int ks = 0; ks < 2; ++ks){
      const u16* src = Ah + (size_t)(m0 + row) * K + Tt * 64 + ks * 32
                     + ((cc ^ ((row >> 1) & 3)) << 3);
      gload_lds16(src, sp_ + ks * KS + (size_t)(h * 64 + w * 16) * 32);
    }
  };
  auto issueB = [&](int Tt, int h, f32x4 (&rb)[4]){
    #pragma unroll
    for (int p = 0; p < 4; ++p){
      int rl = h * 64 + p * 16 + (tid >> 4);
      int gn = n0 + rl; if (gn > NN - 1) gn = NN - 1;
      rb[p] = *reinterpret_cast<const f32x4*>(Bf + (size_t)gn * K + Tt * 64 + (tid & 15) * 4);
    }
  };
  auto publishB = [&](u16* sp_, int h, f32x4 (&rb)[4]){
    int fch = tid & 15;
    int ks  = fch >> 3;
    int c16 = (fch & 7) >> 1;
    int hf  = fch & 1;
    #pragma unroll
    for (int p = 0; p < 4; ++p){
      int row = h * 64 + p * 16 + (tid >> 4);
      uint2 hv;
      hv.x = pkrtz_u32(rb[p][0], rb[p][1]);
      hv.y = pkrtz_u32(rb[p][2], rb[p][3]);
      int phys = c16 ^ ((row >> 1) & 3);
      *reinterpret_cast<uint2*>(sp_ + BOFF + ks * KS + row * 32 + phys * 8 + hf * 4) = hv;
    }
  };

  f32x4 acc[4][4];
  #pragma unroll
  for (int i = 0; i < 4; ++i)
    #pragma unroll
    for (int j = 0; j < 4; ++j)
      acc[i][j] = (f32x4){0.f, 0.f, 0.f, 0.f};

  f32x4 rbB0[4], rbB1[4];
  f16x8 pa[2][2], pb[2][2];

#define READ_PA(SP, MH)                                                        \
  _Pragma("unroll")                                                            \
  for (int ii = 0; ii < 2; ++ii){                                              \
    int row_ = wm * 64 + ((MH) * 2 + ii) * 16 + lr;                            \
    _Pragma("unroll")                                                          \
    for (int ks_ = 0; ks_ < 2; ++ks_)                                          \
      pa[ii][ks_] = __builtin_bit_cast(f16x8, *reinterpret_cast<short8*>(      \
        (SP) + ks_ * KS + row_ * 32 + ((lg ^ ((row_ >> 1) & 3)) << 3)));       \
  }

#define READ_PB(SP, NH)                                                        \
  _Pragma("unroll")                                                            \
  for (int jj = 0; jj < 2; ++jj){                                              \
    int row_ = wn * 64 + ((NH) * 2 + jj) * 16 + lr;                            \
    _Pragma("unroll")                                                          \
    for (int ks_ = 0; ks_ < 2; ++ks_)                                          \
      pb[jj][ks_] = __builtin_bit_cast(f16x8, *reinterpret_cast<short8*>(      \
        (SP) + BOFF + ks_ * KS + row_ * 32 + ((lg ^ ((row_ >> 1) & 3)) << 3)));\
  }

#define MMA(MH, NH)                                                            \
  __builtin_amdgcn_s_setprio(1);                                               \
  _Pragma("unroll")                                                            \
  for (int ii = 0; ii < 2; ++ii)                                               \
    _Pragma("unroll")                                                          \
    for (int jj = 0; jj < 2; ++jj){                                            \
      acc[(MH)*2+ii][(NH)*2+jj] = __builtin_amdgcn_mfma_f32_16x16x32_f16(      \
          pa[ii][0], pb[jj][0], acc[(MH)*2+ii][(NH)*2+jj], 0, 0, 0);           \
      acc[(MH)*2+ii][(NH)*2+jj] = __builtin_amdgcn_mfma_f32_16x16x32_f16(      \
          pa[ii][1], pb[jj][1], acc[(MH)*2+ii][(NH)*2+jj], 0, 0, 0);           \
    }                                                                          \
  __builtin_amdgcn_s_setprio(0);

  glA(lds, 0, 0);  glA(lds, 0, 1);
  SCH;
  issueB(0, 0, rbB0);
  issueB(0, 1, rbB1);
  SCH;
  WAIT_VM(4); SCH;
  publishB(lds, 0, rbB0);
  WAIT_VM(0); SCH;
  publishB(lds, 1, rbB1);
  SCH;
  issueB(1, 0, rbB0);
  issueB(1, 1, rbB1);
  WAIT_LGKM0;
  SB; SCH;

  for (int T = 0; T < NT; ++T){
    u16* sp  = lds + (size_t)(T & 1) * SLOT;
    u16* spn = lds + (size_t)((T + 1) & 1) * SLOT;
    const bool hasN  = (T + 1 < NT);
    const bool hasNN = (T + 2 < NT);

    READ_PA(sp, 0);
    READ_PB(sp, 0);
    if (hasN) glA(spn, T + 1, 0);
    WAIT_LGKM0; SCH;
    MMA(0, 0);

    READ_PB(sp, 1);
    if (hasN){
      glA(spn, T + 1, 1);
      SCH;
      WAIT_VM(8); SCH;
      publishB(spn, 0, rbB0);
      if (hasNN){ issueB(T + 2, 0, rbB0); SCH; }
    }
    WAIT_LGKM0; SCH;
    MMA(0, 1);

    READ_PA(sp, 1);
    if (hasN){
      if (hasNN) { WAIT_VM(8); } else { WAIT_VM(4); }
      SCH;
      publishB(spn, 1, rbB1);
      if (hasNN){ issueB(T + 2, 1, rbB1); SCH; }
    }
    WAIT_LGKM0; SCH;
    MMA(1, 1);

    READ_PB(sp, 0);
    if (hasN){
      if (hasNN) { WAIT_VM(8); } else { WAIT_VM(0); }
      SCH;
    }
    WAIT_LGKM0; SCH;
    MMA(1, 0);
    SCH;
    SB;
  }

#undef READ_PA
#undef READ_PB
#undef MMA

  #pragma unroll
  for (int i = 0; i < 4; ++i){
    int rbase = m0 + wm * 64 + i * 16 + lg * 4;
    #pragma unroll
    for (int j = 0; j < 4; ++j){
      int gcol = n0 + wn * 64 + j * 16 + lr;
      if (gcol < NN){
        #pragma unroll
        for (int r = 0; r < 4; ++r){
          int grow = rbase + r;
          float v = (acc[i][j][r] + rowAdd[grow]) * alpha;
          C[(size_t)grow * NN + gcol] = v;
        }
      }
    }
  }
}

extern "C" void kernel_launch(void* const* d_in, const int* in_sizes, int n_in,
                              void* d_out, int out_size, void* d_ws, size_t ws_size,
                              hipStream_t stream){
  (void)in_sizes; (void)n_in; (void)out_size; (void)ws_size;
  const float* m    = (const float*)d_in[0];   // [512][2048]
  const float* tpl  = (const float*)d_in[1];   // [50000][2048]
  const float* Wmol = (const float*)d_in[2];   // [1024][2048]
  const float* bmol = (const float*)d_in[3];   // [1024]
  const float* Wtmp = (const float*)d_in[4];   // [1024][2048]
  const float* btmp = (const float*)d_in[5];   // [1024]
  float* out = (float*)d_out;                  // [512][50000]

  uint8_t* wp = (uint8_t*)d_ws;
  auto carve = [&](size_t bytes) -> void* {
    void* p = (void*)wp;
    wp += (bytes + 255) & ~(size_t)255;
    return p;
  };
  u16* m_bf   = (u16*)carve((size_t)BB_ * FP_ * 2);
  u16* wm_bf  = (u16*)carve((size_t)AD_ * FP_ * 2);
  u16* wtT_bf = (u16*)carve((size_t)FP_ * AD_ * 2);
  float* Xi   = (float*)carve((size_t)BB_ * AD_ * 4);
  u16* Xi_bf  = (u16*)carve((size_t)BB_ * AD_ * 2);
  u16* Y_hi   = (u16*)carve((size_t)BB_ * FP_ * 2);   // fp16 bits
  float* cvec = (float*)carve((size_t)BB_ * 4);

  // 1) single-bf16 conversions (W_temp also transposed to [FP][A])
  conv_bf_k<<<(BB_ * FP_ / 4 + 255) / 256, 256, 0, stream>>>(m, m_bf, BB_ * FP_);
  conv_bf_k<<<(AD_ * FP_ / 4 + 255) / 256, 256, 0, stream>>>(Wmol, wm_bf, AD_ * FP_);
  conv_bf_T_k<<<dim3(FP_ / 32, AD_ / 32), dim3(32, 8), 0, stream>>>(Wtmp, wtT_bf, AD_, FP_);

  // 2) Xi = m @ W_mol^T + b_mol   [512 x 1024], K=2048  (fp32 + bf16 out)
  gemm_s<64, 64, 2, 2, 1><<<dim3(BB_ / 64, AD_ / 64), 256, 0, stream>>>(
      m_bf, wm_bf, BB_, AD_, FP_, Xi, Xi_bf, bmol);

  // 3) c[b] = Xi[b,:] . b_temp
  dot_rows_k<<<BB_ / 4, 256, 0, stream>>>(Xi, btmp, cvec, AD_);

  // 4) Y = Xi @ W_temp   [512 x 2048], K=1024  -> fp16 single
  gemm_s<64, 64, 2, 2, 2><<<dim3(BB_ / 64, FP_ / 64), 256, 0, stream>>>(
      Xi_bf, wtT_bf, BB_, FP_, AD_, nullptr, Y_hi, nullptr);

  // 5) out = BETA * (Y @ templates^T + c)   [512 x 50000], K=2048
  //    Phase 1: strips 0..127 as 256 full tiles (exactly 1 block/CU, 1 round).
  gemm_big<<<256, 512, 0, stream>>>(Y_hi, tpl, out, cvec, BETA_);
  //    Phase 2: strips 128..195 as 544 quarter tiles (2 blocks/CU).
  gemm_q<<<544, 256, 0, stream>>>(Y_hi, tpl, out, cvec, BETA_);
}

// Round 20
// 233.812 us; speedup vs baseline: 1.0619x; 1.0619x over previous
//
#include <hip/hip_runtime.h>
#include <cstdint>
#include <cstddef>

typedef __attribute__((ext_vector_type(8))) short short8;     // 8 x 16-bit (4 VGPRs)
typedef __attribute__((ext_vector_type(8))) _Float16 f16x8;   // fp16 MFMA frag
typedef __attribute__((ext_vector_type(4))) float f32x4;
typedef __attribute__((ext_vector_type(4))) unsigned short u16x4;
typedef unsigned short u16;

#define FP_  2048
#define AD_  1024
#define BB_  512
#define TT_  50000
#define BETA_ 0.125f

// ---------- fp32 -> bf16 (RNE) helpers ----------
__device__ __forceinline__ u16 f2bf(float x){
  uint32_t u = __builtin_bit_cast(uint32_t, x);
  u = (u + 0x7fffu + ((u >> 16) & 1u)) >> 16;
  return (u16)u;
}
__device__ __forceinline__ u16 f2h_bits(float x){
  _Float16 h = (_Float16)x;            // RNE
  return __builtin_bit_cast(u16, h);
}
__device__ __forceinline__ unsigned int pkrtz_u32(float a, float b){
  return __builtin_bit_cast(unsigned int, __builtin_amdgcn_cvt_pkrtz(a, b));
}
__device__ __forceinline__ short8 cvt8_bf(const f32x4& a, const f32x4& b){
  short8 r;
  r[0] = (short)f2bf(a[0]); r[1] = (short)f2bf(a[1]);
  r[2] = (short)f2bf(a[2]); r[3] = (short)f2bf(a[3]);
  r[4] = (short)f2bf(b[0]); r[5] = (short)f2bf(b[1]);
  r[6] = (short)f2bf(b[2]); r[7] = (short)f2bf(b[3]);
  return r;
}

// ---------- async global->LDS, 16B per lane ----------
__device__ __forceinline__ void gload_lds16(const void* g, void* l){
  __builtin_amdgcn_global_load_lds((const __attribute__((address_space(1))) void*)g,
                                   (__attribute__((address_space(3))) void*)l,
                                   16, 0, 0);
}

#define SB   __builtin_amdgcn_s_barrier()
#define SCH  __builtin_amdgcn_sched_barrier(0)
#define WAIT_LGKM0 asm volatile("s_waitcnt lgkmcnt(0)" ::: "memory")
#define WAIT_VM(n) asm volatile("s_waitcnt vmcnt(" #n ")" ::: "memory")

// ---------- W[R][C] -> out[C][R] bf16 single (LDS tile transpose) ----------
__global__ void conv_bf_T_k(const float* __restrict__ W, u16* __restrict__ outT,
                            int R, int C){
  __shared__ float tile[32][33];
  int c0 = blockIdx.x * 32;
  int r0 = blockIdx.y * 32;
  int tx = threadIdx.x;   // 0..31
  int ty = threadIdx.y;   // 0..7
  #pragma unroll
  for (int i = 0; i < 32; i += 8)
    tile[ty + i][tx] = W[(size_t)(r0 + ty + i) * C + c0 + tx];
  __syncthreads();
  #pragma unroll
  for (int i = 0; i < 32; i += 8){
    float x = tile[tx][ty + i];              // = W[r0+tx][c0+ty+i]
    outT[(size_t)(c0 + ty + i) * R + r0 + tx] = f2bf(x);
  }
}

// ---------- c[b] = dot(Xi[b,:], b_temp) : one wave per row ----------
__global__ void dot_rows_k(const float* __restrict__ Xi, const float* __restrict__ bt,
                           float* __restrict__ c, int K){
  int row  = blockIdx.x * 4 + (threadIdx.x >> 6);
  int lane = threadIdx.x & 63;
  float s = 0.f;
  for (int a = lane; a < K; a += 64) s += Xi[(size_t)row * K + a] * bt[a];
  #pragma unroll
  for (int off = 32; off; off >>= 1) s += __shfl_down(s, off);
  if (lane == 0) c[row] = s;
}

// ---------- single-bf16 small GEMM: C = A·B^T + colBias ----------
// OUT: 1 = fp32 + bf16 (Xi), 2 = fp16 bits (Y)
// AF32/BF32: operand supplied as fp32, converted to bf16 during staging.
template<int TM, int TN, int FM, int FN, int OUT, bool AF32, bool BF32>
__global__ __launch_bounds__(256, 2)
void gemm_s(const void* __restrict__ Av, const void* __restrict__ Bv,
            int M, int N, int K,
            float* __restrict__ Cf, u16* __restrict__ C16,
            const float* __restrict__ colBias)
{
  constexpr int BK = 32;
  constexpr int WM = TM / (16 * FM);
  constexpr int WN = TN / (16 * FN);
  static_assert(WM * WN == 4, "4 waves / 256 threads");
  constexpr int BUFE = (TM + TN) * BK;

  __shared__ __align__(16) u16 lds[2 * BUFE];

  const int m0 = blockIdx.x * TM;
  const int n0 = blockIdx.y * TN;

  const int tid  = threadIdx.x;
  const int w    = tid >> 6;
  const int lane = tid & 63;
  const int lr   = lane & 15;
  const int lg   = lane >> 4;
  const int wm   = w / WN;
  const int wn   = w % WN;

  const int rrA = tid >> 2;     // 0..63 (row)
  const int chA = tid & 3;      // 8-elem chunk

  short8 ra, rb;
  f32x4  raf0, raf1, rbf0, rbf1;

  f32x4 acc[FM][FN];
  #pragma unroll
  for (int i = 0; i < FM; ++i)
    #pragma unroll
    for (int j = 0; j < FN; ++j)
      acc[i][j] = (f32x4){0.f, 0.f, 0.f, 0.f};

  auto stage_load = [&](int k0){
    int gm = m0 + rrA;
    if constexpr (AF32){
      const float* Af = (const float*)Av;
      raf0 = *reinterpret_cast<const f32x4*>(Af + (size_t)gm * K + k0 + chA * 8);
      raf1 = *reinterpret_cast<const f32x4*>(Af + (size_t)gm * K + k0 + chA * 8 + 4);
    } else {
      const u16* Ab = (const u16*)Av;
      ra = *reinterpret_cast<const short8*>(Ab + (size_t)gm * K + k0 + chA * 8);
    }
    int gn = n0 + rrA; if (gn > N - 1) gn = N - 1;
    if constexpr (BF32){
      const float* Bf = (const float*)Bv;
      rbf0 = *reinterpret_cast<const f32x4*>(Bf + (size_t)gn * K + k0 + chA * 8);
      rbf1 = *reinterpret_cast<const f32x4*>(Bf + (size_t)gn * K + k0 + chA * 8 + 4);
    } else {
      const u16* Bb = (const u16*)Bv;
      rb = *reinterpret_cast<const short8*>(Bb + (size_t)gn * K + k0 + chA * 8);
    }
  };
  auto stage_store = [&](int buf){
    u16* As = lds + buf * BUFE;
    u16* Bs = As + TM * BK;
    int row = rrA;
    int sw  = (chA ^ ((row >> 1) & 3)) << 3;
    short8 va = AF32 ? cvt8_bf(raf0, raf1) : ra;
    short8 vb = BF32 ? cvt8_bf(rbf0, rbf1) : rb;
    *reinterpret_cast<short8*>(As + row * BK + sw) = va;
    *reinterpret_cast<short8*>(Bs + row * BK + sw) = vb;
  };

  const int NT = K / BK;
  stage_load(0);
  stage_store(0);
  __syncthreads();

  int cur = 0;
  for (int t = 0; t < NT; ++t){
    const bool have_next = (t + 1 < NT);
    if (have_next) stage_load((t + 1) * BK);

    u16* As = lds + cur * BUFE;
    u16* Bs = As + TM * BK;

    short8 ah[FM], bh[FN];
    #pragma unroll
    for (int i = 0; i < FM; ++i){
      int row = wm * FM * 16 + i * 16 + lr;
      int off = row * BK + ((lg ^ ((row >> 1) & 3)) << 3);
      ah[i] = *reinterpret_cast<short8*>(As + off);
    }
    #pragma unroll
    for (int j = 0; j < FN; ++j){
      int row = wn * FN * 16 + j * 16 + lr;
      int off = row * BK + ((lg ^ ((row >> 1) & 3)) << 3);
      bh[j] = *reinterpret_cast<short8*>(Bs + off);
    }
    #pragma unroll
    for (int i = 0; i < FM; ++i)
      #pragma unroll
      for (int j = 0; j < FN; ++j)
        acc[i][j] = __builtin_amdgcn_mfma_f32_16x16x32_bf16(ah[i], bh[j], acc[i][j], 0, 0, 0);

    if (have_next){
      __builtin_amdgcn_sched_barrier(0);
      stage_store(cur ^ 1);
      __syncthreads();
    }
    cur ^= 1;
  }

  #pragma unroll
  for (int i = 0; i < FM; ++i){
    int rbase = m0 + wm * FM * 16 + i * 16 + lg * 4;
    #pragma unroll
    for (int j = 0; j < FN; ++j){
      int gcol = n0 + wn * FN * 16 + j * 16 + lr;
      if (gcol < N){
        float cb = colBias ? colBias[gcol] : 0.f;
        #pragma unroll
        for (int r = 0; r < 4; ++r){
          int grow = rbase + r;
          float v = acc[i][j][r] + cb;
          size_t idx = (size_t)grow * N + gcol;
          if constexpr (OUT == 1){
            Cf[idx]  = v;
            C16[idx] = f2bf(v);
          } else {
            C16[idx] = f2h_bits(v);
          }
        }
      }
    }
  }
}

// ---------- BIG GEMM: 256x256 Gray-code phases, DE-LOCKSTEPPED (R16/R18 best) ----------
// out = alpha*(A·B^T + rowAdd). A = Y fp16 [512][2048] (L2-res., global_load_lds);
// B = fp32 templates, reg-staged 1.5 K-tiles ahead, pkrtz-published into the
// NEXT dbuf slot during phases B/C.
// De-lockstep: NO intra-tile barriers; ONE boundary s_barrier per K-tile.
// Ledger: entering T = [B0(T+1):4, B1(T+1):4] = 8; phase B VM(8),
// phase C VM(8|4), phase D VM(8|0).
__global__ __launch_bounds__(512, 1)
void gemm_big(const u16* __restrict__ Ah,      // fp16 bits [512][2048]
              const float* __restrict__ Bf,    // [50000][2048]
              float* __restrict__ C,
              const float* __restrict__ rowAdd, float alpha)
{
  constexpr int K = FP_, NN = TT_;
  constexpr int NT = K / 64;                  // 32 K-tiles
  constexpr int KS = 8192;                    // u16 per ksub block (256x32)
  constexpr int BOFF = 16384;                 // B region offset (u16)
  constexpr int SLOT = 32768;                 // u16 per slot (64KB)

  __shared__ __align__(16) u16 lds[2 * SLOT]; // 128KB

  // XCD-bijective: 196 N-tiles of 256; xcd<4 own 25 strips, xcd>=4 own 24.
  int id  = blockIdx.x;
  int xcd = id & 7;
  int g   = id >> 3;          // 0..49
  int mt  = g & 1;            // 2 M-tiles of 256
  int sg  = g >> 1;           // 0..24
  int strips = (xcd < 4) ? 25 : 24;
  if (sg >= strips) return;
  int nt = ((xcd < 4) ? xcd * 25 : 100 + (xcd - 4) * 24) + sg;   // 0..195
  const int m0 = mt * 256;
  const int n0 = nt * 256;

  const int tid  = threadIdx.x;     // 0..511
  const int w    = tid >> 6;        // 0..7
  const int lane = tid & 63;
  const int lr   = lane & 15;
  const int lg   = lane >> 4;
  const int wm   = w >> 2;          // 0..1 (128-row band)
  const int wn   = w & 3;           // 0..3 (64-col band)

  // ---- A: global_load_lds, 2 calls per half (ks=0,1), linear dest ----
  auto glA = [&](u16* sp_, int Tt, int h){
    int rl = lane >> 2;             // 0..15
    int cc = lane & 3;              // 16B chunk of 64B row
    int row = h * 128 + w * 16 + rl;
    #pragma unroll
    for (int ks = 0; ks < 2; ++ks){
      const u16* src = Ah + (size_t)(m0 + row) * K + Tt * 64 + ks * 32
                     + ((cc ^ ((row >> 1) & 3)) << 3);
      gload_lds16(src, sp_ + ks * KS + (size_t)(h * 128 + w * 16) * 32);
    }
  };
  // ---- B: 4 coalesced f32x4 loads per thread per half ----
  auto issueB = [&](int Tt, int h, f32x4 (&rb)[4]){
    #pragma unroll
    for (int p = 0; p < 4; ++p){
      int rl = h * 128 + p * 32 + (tid >> 4);
      int gn = n0 + rl; if (gn > NN - 1) gn = NN - 1;
      rb[p] = *reinterpret_cast<const f32x4*>(Bf + (size_t)gn * K + Tt * 64 + (tid & 15) * 4);
    }
  };
  auto publishB = [&](u16* sp_, int h, f32x4 (&rb)[4]){
    int fch = tid & 15;
    int ks  = fch >> 3;
    int c16 = (fch & 7) >> 1;
    int hf  = fch & 1;
    #pragma unroll
    for (int p = 0; p < 4; ++p){
      int row = h * 128 + p * 32 + (tid >> 4);
      uint2 hv;
      hv.x = pkrtz_u32(rb[p][0], rb[p][1]);
      hv.y = pkrtz_u32(rb[p][2], rb[p][3]);
      int phys = c16 ^ ((row >> 1) & 3);
      *reinterpret_cast<uint2*>(sp_ + BOFF + ks * KS + row * 32 + phys * 8 + hf * 4) = hv;
    }
  };

  f32x4 acc[8][4];
  #pragma unroll
  for (int i = 0; i < 8; ++i)
    #pragma unroll
    for (int j = 0; j < 4; ++j)
      acc[i][j] = (f32x4){0.f, 0.f, 0.f, 0.f};

  f32x4 rbB0[4], rbB1[4];           // B-half reg sets (static names)
  f16x8 pa[4][2], pb[2][2];         // live fragment registers (Gray-reused)

#define READ_PA(SP, MH)                                                        \
  _Pragma("unroll")                                                            \
  for (int ii = 0; ii < 4; ++ii){                                              \
    int row_ = wm * 128 + ((MH) * 4 + ii) * 16 + lr;                           \
    _Pragma("unroll")                                                          \
    for (int ks_ = 0; ks_ < 2; ++ks_)                                          \
      pa[ii][ks_] = __builtin_bit_cast(f16x8, *reinterpret_cast<short8*>(      \
        (SP) + ks_ * KS + row_ * 32 + ((lg ^ ((row_ >> 1) & 3)) << 3)));       \
  }

#define READ_PB(SP, NH)                                                        \
  _Pragma("unroll")                                                            \
  for (int jj = 0; jj < 2; ++jj){                                              \
    int row_ = wn * 64 + ((NH) * 2 + jj) * 16 + lr;                            \
    _Pragma("unroll")                                                          \
    for (int ks_ = 0; ks_ < 2; ++ks_)                                          \
      pb[jj][ks_] = __builtin_bit_cast(f16x8, *reinterpret_cast<short8*>(      \
        (SP) + BOFF + ks_ * KS + row_ * 32 + ((lg ^ ((row_ >> 1) & 3)) << 3)));\
  }

#define MMA(MH, NH)                                                            \
  __builtin_amdgcn_s_setprio(1);                                               \
  _Pragma("unroll")                                                            \
  for (int ii = 0; ii < 4; ++ii)                                               \
    _Pragma("unroll")                                                          \
    for (int jj = 0; jj < 2; ++jj){                                            \
      acc[(MH)*4+ii][(NH)*2+jj] = __builtin_amdgcn_mfma_f32_16x16x32_f16(      \
          pa[ii][0], pb[jj][0], acc[(MH)*4+ii][(NH)*2+jj], 0, 0, 0);           \
      acc[(MH)*4+ii][(NH)*2+jj] = __builtin_amdgcn_mfma_f32_16x16x32_f16(      \
          pa[ii][1], pb[jj][1], acc[(MH)*4+ii][(NH)*2+jj], 0, 0, 0);           \
    }                                                                          \
  __builtin_amdgcn_s_setprio(0);

  // ---- prologue: tile0 staged+published into slot0; B(1) sets in flight ----
  glA(lds, 0, 0);  glA(lds, 0, 1);    // 4 entries
  SCH;
  issueB(0, 0, rbB0);                 // 8
  issueB(0, 1, rbB1);                 // 12
  SCH;
  WAIT_VM(4); SCH;                    // A(0) + B0(0) retired
  publishB(lds, 0, rbB0);
  WAIT_VM(0); SCH;                    // B1(0) retired
  publishB(lds, 1, rbB1);
  SCH;
  issueB(1, 0, rbB0);                 // 4
  issueB(1, 1, rbB1);                 // 8
  WAIT_LGKM0;
  SB; SCH;
  // entering T=0: outstanding [B0(1):4, B1(1):4] = 8  (invariant)

  for (int T = 0; T < NT; ++T){
    u16* sp  = lds + (size_t)(T & 1) * SLOT;
    u16* spn = lds + (size_t)((T + 1) & 1) * SLOT;
    const bool hasN  = (T + 1 < NT);
    const bool hasNN = (T + 2 < NT);

    // ---- phase A: quadrant (0,0); stage A0(T+1) ----
    READ_PA(sp, 0);
    READ_PB(sp, 0);
    if (hasN) glA(spn, T + 1, 0);
    WAIT_LGKM0; SCH;
    MMA(0, 0);

    // ---- phase B: quadrant (0,1); stage A1(T+1); publish B0(T+1); issue B0(T+2) ----
    READ_PB(sp, 1);
    if (hasN){
      glA(spn, T + 1, 1);
      SCH;
      WAIT_VM(8); SCH;                         // B0(T+1) retired
      publishB(spn, 0, rbB0);
      if (hasNN){ issueB(T + 2, 0, rbB0); SCH; }
    }
    WAIT_LGKM0; SCH;
    MMA(0, 1);

    // ---- phase C: quadrant (1,1); publish B1(T+1); issue B1(T+2) ----
    READ_PA(sp, 1);
    if (hasN){
      if (hasNN) { WAIT_VM(8); } else { WAIT_VM(4); }   // B1(T+1) retired
      SCH;
      publishB(spn, 1, rbB1);
      if (hasNN){ issueB(T + 2, 1, rbB1); SCH; }
    }
    WAIT_LGKM0; SCH;
    MMA(1, 1);

    // ---- phase D: quadrant (1,0); confirm A(T+1) landed; boundary barrier ----
    READ_PB(sp, 0);
    if (hasN){
      if (hasNN) { WAIT_VM(8); } else { WAIT_VM(0); }   // A(T+1) in LDS
      SCH;
    }
    WAIT_LGKM0; SCH;
    MMA(1, 0);
    SCH;
    SB;                                // ONE barrier per K-tile (slot swap)
  }

#undef READ_PA
#undef READ_PB
#undef MMA

  // ---- epilogue: row=(lane>>4)*4+reg (A idx), col=lane&15 (B idx) ----
  #pragma unroll
  for (int i = 0; i < 8; ++i){
    int rbase = m0 + wm * 128 + i * 16 + lg * 4;
    #pragma unroll
    for (int j = 0; j < 4; ++j){
      int gcol = n0 + wn * 64 + j * 16 + lr;
      if (gcol < NN){
        #pragma unroll
        for (int r = 0; r < 4; ++r){
          int grow = rbase + r;
          float v = (acc[i][j][r] + rowAdd[grow]) * alpha;
          C[(size_t)grow * NN + gcol] = v;
        }
      }
    }
  }
}

extern "C" void kernel_launch(void* const* d_in, const int* in_sizes, int n_in,
                              void* d_out, int out_size, void* d_ws, size_t ws_size,
                              hipStream_t stream){
  (void)in_sizes; (void)n_in; (void)out_size; (void)ws_size;
  const float* m    = (const float*)d_in[0];   // [512][2048]
  const float* tpl  = (const float*)d_in[1];   // [50000][2048]
  const float* Wmol = (const float*)d_in[2];   // [1024][2048]
  const float* bmol = (const float*)d_in[3];   // [1024]
  const float* Wtmp = (const float*)d_in[4];   // [1024][2048]
  const float* btmp = (const float*)d_in[5];   // [1024]
  float* out = (float*)d_out;                  // [512][50000]

  uint8_t* wp = (uint8_t*)d_ws;
  auto carve = [&](size_t bytes) -> void* {
    void* p = (void*)wp;
    wp += (bytes + 255) & ~(size_t)255;
    return p;
  };
  u16* wtT_bf = (u16*)carve((size_t)FP_ * AD_ * 2);
  float* Xi   = (float*)carve((size_t)BB_ * AD_ * 4);
  u16* Xi_bf  = (u16*)carve((size_t)BB_ * AD_ * 2);
  u16* Y_hi   = (u16*)carve((size_t)BB_ * FP_ * 2);   // fp16 bits
  float* cvec = (float*)carve((size_t)BB_ * 4);

  // 1) W_temp transpose+convert to bf16 [FP][A] (only conversion kernel left)
  conv_bf_T_k<<<dim3(FP_ / 32, AD_ / 32), dim3(32, 8), 0, stream>>>(Wtmp, wtT_bf, AD_, FP_);

  // 2) Xi = m @ W_mol^T + b_mol  [512 x 1024], K=2048
  //    fp32 operands converted to bf16 in the staging path (fused conversions).
  gemm_s<64, 64, 2, 2, 1, true, true><<<dim3(BB_ / 64, AD_ / 64), 256, 0, stream>>>(
      m, Wmol, BB_, AD_, FP_, Xi, Xi_bf, bmol);

  // 3) c[b] = Xi[b,:] . b_temp
  dot_rows_k<<<BB_ / 4, 256, 0, stream>>>(Xi, btmp, cvec, AD_);

  // 4) Y = Xi @ W_temp   [512 x 2048], K=1024  -> fp16 single
  gemm_s<64, 64, 2, 2, 2, false, false><<<dim3(BB_ / 64, FP_ / 64), 256, 0, stream>>>(
      Xi_bf, wtT_bf, BB_, FP_, AD_, nullptr, Y_hi, nullptr);

  // 5) out = BETA * (Y @ templates^T + c)   [512 x 50000], K=2048
  //    400 blocks = 8 XCD x (2 M-tiles x 25 strip-slots); 8 masked. 1 block/CU.
  gemm_big<<<400, 512, 0, stream>>>(Y_hi, tpl, out, cvec, BETA_);
}

// Round 21
// 213.604 us; speedup vs baseline: 1.1624x; 1.0946x over previous
//
#include <hip/hip_runtime.h>
#include <cstdint>
#include <cstddef>

typedef __attribute__((ext_vector_type(8))) short short8;     // 8 x 16-bit (4 VGPRs)
typedef __attribute__((ext_vector_type(8))) _Float16 f16x8;   // fp16 MFMA frag
typedef __attribute__((ext_vector_type(4))) float f32x4;
typedef __attribute__((ext_vector_type(4))) unsigned short u16x4;
typedef unsigned short u16;

#define FP_  2048
#define AD_  1024
#define BB_  512
#define TT_  50000
#define BETA_ 0.125f

// ---------- fp32 -> bf16 (RNE) helpers ----------
__device__ __forceinline__ u16 f2bf(float x){
  uint32_t u = __builtin_bit_cast(uint32_t, x);
  u = (u + 0x7fffu + ((u >> 16) & 1u)) >> 16;
  return (u16)u;
}
__device__ __forceinline__ u16 f2h_bits(float x){
  _Float16 h = (_Float16)x;            // RNE
  return __builtin_bit_cast(u16, h);
}
__device__ __forceinline__ unsigned int pkrtz_u32(float a, float b){
  return __builtin_bit_cast(unsigned int, __builtin_amdgcn_cvt_pkrtz(a, b));
}

// ---------- async global->LDS, 16B per lane ----------
__device__ __forceinline__ void gload_lds16(const void* g, void* l){
  __builtin_amdgcn_global_load_lds((const __attribute__((address_space(1))) void*)g,
                                   (__attribute__((address_space(3))) void*)l,
                                   16, 0, 0);
}

#define SB   __builtin_amdgcn_s_barrier()
#define SCH  __builtin_amdgcn_sched_barrier(0)
#define WAIT_LGKM0 asm volatile("s_waitcnt lgkmcnt(0)" ::: "memory")
#define WAIT_VM(n) asm volatile("s_waitcnt vmcnt(" #n ")" ::: "memory")

// ---------- elementwise fp32 -> bf16 (single) ----------
__global__ void conv_bf_k(const float* __restrict__ src, u16* __restrict__ dst, int n){
  int i = (blockIdx.x * blockDim.x + threadIdx.x) * 4;
  if (i >= n) return;
  f32x4 v = *reinterpret_cast<const f32x4*>(src + i);
  u16x4 h;
  #pragma unroll
  for (int e = 0; e < 4; ++e) h[e] = f2bf(v[e]);
  *reinterpret_cast<u16x4*>(dst + i) = h;
}

// ---------- W[R][C] -> out[C][R] bf16 single (LDS tile transpose) ----------
__global__ void conv_bf_T_k(const float* __restrict__ W, u16* __restrict__ outT,
                            int R, int C){
  __shared__ float tile[32][33];
  int c0 = blockIdx.x * 32;
  int r0 = blockIdx.y * 32;
  int tx = threadIdx.x;   // 0..31
  int ty = threadIdx.y;   // 0..7
  #pragma unroll
  for (int i = 0; i < 32; i += 8)
    tile[ty + i][tx] = W[(size_t)(r0 + ty + i) * C + c0 + tx];
  __syncthreads();
  #pragma unroll
  for (int i = 0; i < 32; i += 8){
    float x = tile[tx][ty + i];              // = W[r0+tx][c0+ty+i]
    outT[(size_t)(c0 + ty + i) * R + r0 + tx] = f2bf(x);
  }
}

// ---------- c[b] = dot(Xi[b,:], b_temp) : one wave per row ----------
__global__ void dot_rows_k(const float* __restrict__ Xi, const float* __restrict__ bt,
                           float* __restrict__ c, int K){
  int row  = blockIdx.x * 4 + (threadIdx.x >> 6);
  int lane = threadIdx.x & 63;
  float s = 0.f;
  for (int a = lane; a < K; a += 64) s += Xi[(size_t)row * K + a] * bt[a];
  #pragma unroll
  for (int off = 32; off; off >>= 1) s += __shfl_down(s, off);
  if (lane == 0) c[row] = s;
}

// ---------- single-bf16 small GEMM: C = A·B^T + colBias ----------
// OUT: 1 = fp32 + bf16 (Xi), 2 = fp16 bits (Y)
template<int TM, int TN, int FM, int FN, int OUT>
__global__ __launch_bounds__(256, 2)
void gemm_s(const u16* __restrict__ A, const u16* __restrict__ B,
            int M, int N, int K,
            float* __restrict__ Cf, u16* __restrict__ C16,
            const float* __restrict__ colBias)
{
  constexpr int BK = 32;
  constexpr int WM = TM / (16 * FM);
  constexpr int WN = TN / (16 * FN);
  static_assert(WM * WN == 4, "4 waves / 256 threads");
  constexpr int BUFE = (TM + TN) * BK;

  __shared__ __align__(16) u16 lds[2 * BUFE];

  const int m0 = blockIdx.x * TM;
  const int n0 = blockIdx.y * TN;

  const int tid  = threadIdx.x;
  const int w    = tid >> 6;
  const int lane = tid & 63;
  const int lr   = lane & 15;
  const int lg   = lane >> 4;
  const int wm   = w / WN;
  const int wn   = w % WN;

  const int rrA = tid >> 2;     // 0..63
  const int chA = tid & 3;      // 16B chunk

  short8 ra, rb;

  f32x4 acc[FM][FN];
  #pragma unroll
  for (int i = 0; i < FM; ++i)
    #pragma unroll
    for (int j = 0; j < FN; ++j)
      acc[i][j] = (f32x4){0.f, 0.f, 0.f, 0.f};

  auto stage_load = [&](int k0){
    int gm = m0 + rrA;
    ra = *reinterpret_cast<const short8*>(A + (size_t)gm * K + k0 + chA * 8);
    int gn = n0 + rrA; if (gn > N - 1) gn = N - 1;
    rb = *reinterpret_cast<const short8*>(B + (size_t)gn * K + k0 + chA * 8);
  };
  auto stage_store = [&](int buf){
    u16* As = lds + buf * BUFE;
    u16* Bs = As + TM * BK;
    int row = rrA;
    int sw  = (chA ^ ((row >> 1) & 3)) << 3;
    *reinterpret_cast<short8*>(As + row * BK + sw) = ra;
    *reinterpret_cast<short8*>(Bs + row * BK + sw) = rb;
  };

  const int NT = K / BK;
  stage_load(0);
  stage_store(0);
  __syncthreads();

  int cur = 0;
  for (int t = 0; t < NT; ++t){
    const bool have_next = (t + 1 < NT);
    if (have_next) stage_load((t + 1) * BK);

    u16* As = lds + cur * BUFE;
    u16* Bs = As + TM * BK;

    short8 ah[FM], bh[FN];
    #pragma unroll
    for (int i = 0; i < FM; ++i){
      int row = wm * FM * 16 + i * 16 + lr;
      int off = row * BK + ((lg ^ ((row >> 1) & 3)) << 3);
      ah[i] = *reinterpret_cast<short8*>(As + off);
    }
    #pragma unroll
    for (int j = 0; j < FN; ++j){
      int row = wn * FN * 16 + j * 16 + lr;
      int off = row * BK + ((lg ^ ((row >> 1) & 3)) << 3);
      bh[j] = *reinterpret_cast<short8*>(Bs + off);
    }
    #pragma unroll
    for (int i = 0; i < FM; ++i)
      #pragma unroll
      for (int j = 0; j < FN; ++j)
        acc[i][j] = __builtin_amdgcn_mfma_f32_16x16x32_bf16(ah[i], bh[j], acc[i][j], 0, 0, 0);

    if (have_next){
      __builtin_amdgcn_sched_barrier(0);
      stage_store(cur ^ 1);
      __syncthreads();
    }
    cur ^= 1;
  }

  #pragma unroll
  for (int i = 0; i < FM; ++i){
    int rbase = m0 + wm * FM * 16 + i * 16 + lg * 4;
    #pragma unroll
    for (int j = 0; j < FN; ++j){
      int gcol = n0 + wn * FN * 16 + j * 16 + lr;
      if (gcol < N){
        float cb = colBias ? colBias[gcol] : 0.f;
        #pragma unroll
        for (int r = 0; r < 4; ++r){
          int grow = rbase + r;
          float v = acc[i][j][r] + cb;
          size_t idx = (size_t)grow * N + gcol;
          if constexpr (OUT == 1){
            Cf[idx]  = v;
            C16[idx] = f2bf(v);
          } else {
            C16[idx] = f2h_bits(v);
          }
        }
      }
    }
  }
}

// ---------- BIG GEMM: 256x256 Gray-code phases, DE-LOCKSTEPPED (R16/R18 best) ----------
// out = alpha*(A·B^T + rowAdd). A = Y fp16 [512][2048] (L2-res., global_load_lds);
// B = fp32 templates, reg-staged 1.5 K-tiles ahead, pkrtz-published into the
// NEXT dbuf slot during phases B/C.
// De-lockstep: NO intra-tile barriers; ONE boundary s_barrier per K-tile.
// Ledger: entering T = [B0(T+1):4, B1(T+1):4] = 8; phase B VM(8),
// phase C VM(8|4), phase D VM(8|0).
__global__ __launch_bounds__(512, 1)
void gemm_big(const u16* __restrict__ Ah,      // fp16 bits [512][2048]
              const float* __restrict__ Bf,    // [50000][2048]
              float* __restrict__ C,
              const float* __restrict__ rowAdd, float alpha)
{
  constexpr int K = FP_, NN = TT_;
  constexpr int NT = K / 64;                  // 32 K-tiles
  constexpr int KS = 8192;                    // u16 per ksub block (256x32)
  constexpr int BOFF = 16384;                 // B region offset (u16)
  constexpr int SLOT = 32768;                 // u16 per slot (64KB)

  __shared__ __align__(16) u16 lds[2 * SLOT]; // 128KB

  // XCD-bijective: 196 N-tiles of 256; xcd<4 own 25 strips, xcd>=4 own 24.
  int id  = blockIdx.x;
  int xcd = id & 7;
  int g   = id >> 3;          // 0..49
  int mt  = g & 1;            // 2 M-tiles of 256
  int sg  = g >> 1;           // 0..24
  int strips = (xcd < 4) ? 25 : 24;
  if (sg >= strips) return;
  int nt = ((xcd < 4) ? xcd * 25 : 100 + (xcd - 4) * 24) + sg;   // 0..195
  const int m0 = mt * 256;
  const int n0 = nt * 256;

  const int tid  = threadIdx.x;     // 0..511
  const int w    = tid >> 6;        // 0..7
  const int lane = tid & 63;
  const int lr   = lane & 15;
  const int lg   = lane >> 4;
  const int wm   = w >> 2;          // 0..1 (128-row band)
  const int wn   = w & 3;           // 0..3 (64-col band)

  // ---- A: global_load_lds, 2 calls per half (ks=0,1), linear dest ----
  auto glA = [&](u16* sp_, int Tt, int h){
    int rl = lane >> 2;             // 0..15
    int cc = lane & 3;              // 16B chunk of 64B row
    int row = h * 128 + w * 16 + rl;
    #pragma unroll
    for (int ks = 0; ks < 2; ++ks){
      const u16* src = Ah + (size_t)(m0 + row) * K + Tt * 64 + ks * 32
                     + ((cc ^ ((row >> 1) & 3)) << 3);
      gload_lds16(src, sp_ + ks * KS + (size_t)(h * 128 + w * 16) * 32);
    }
  };
  // ---- B: 4 coalesced f32x4 loads per thread per half ----
  auto issueB = [&](int Tt, int h, f32x4 (&rb)[4]){
    #pragma unroll
    for (int p = 0; p < 4; ++p){
      int rl = h * 128 + p * 32 + (tid >> 4);
      int gn = n0 + rl; if (gn > NN - 1) gn = NN - 1;
      rb[p] = *reinterpret_cast<const f32x4*>(Bf + (size_t)gn * K + Tt * 64 + (tid & 15) * 4);
    }
  };
  auto publishB = [&](u16* sp_, int h, f32x4 (&rb)[4]){
    int fch = tid & 15;
    int ks  = fch >> 3;
    int c16 = (fch & 7) >> 1;
    int hf  = fch & 1;
    #pragma unroll
    for (int p = 0; p < 4; ++p){
      int row = h * 128 + p * 32 + (tid >> 4);
      uint2 hv;
      hv.x = pkrtz_u32(rb[p][0], rb[p][1]);
      hv.y = pkrtz_u32(rb[p][2], rb[p][3]);
      int phys = c16 ^ ((row >> 1) & 3);
      *reinterpret_cast<uint2*>(sp_ + BOFF + ks * KS + row * 32 + phys * 8 + hf * 4) = hv;
    }
  };

  f32x4 acc[8][4];
  #pragma unroll
  for (int i = 0; i < 8; ++i)
    #pragma unroll
    for (int j = 0; j < 4; ++j)
      acc[i][j] = (f32x4){0.f, 0.f, 0.f, 0.f};

  f32x4 rbB0[4], rbB1[4];           // B-half reg sets (static names)
  f16x8 pa[4][2], pb[2][2];         // live fragment registers (Gray-reused)

#define READ_PA(SP, MH)                                                        \
  _Pragma("unroll")                                                            \
  for (int ii = 0; ii < 4; ++ii){                                              \
    int row_ = wm * 128 + ((MH) * 4 + ii) * 16 + lr;                           \
    _Pragma("unroll")                                                          \
    for (int ks_ = 0; ks_ < 2; ++ks_)                                          \
      pa[ii][ks_] = __builtin_bit_cast(f16x8, *reinterpret_cast<short8*>(      \
        (SP) + ks_ * KS + row_ * 32 + ((lg ^ ((row_ >> 1) & 3)) << 3)));       \
  }

#define READ_PB(SP, NH)                                                        \
  _Pragma("unroll")                                                            \
  for (int jj = 0; jj < 2; ++jj){                                              \
    int row_ = wn * 64 + ((NH) * 2 + jj) * 16 + lr;                            \
    _Pragma("unroll")                                                          \
    for (int ks_ = 0; ks_ < 2; ++ks_)                                          \
      pb[jj][ks_] = __builtin_bit_cast(f16x8, *reinterpret_cast<short8*>(      \
        (SP) + BOFF + ks_ * KS + row_ * 32 + ((lg ^ ((row_ >> 1) & 3)) << 3)));\
  }

#define MMA(MH, NH)                                                            \
  __builtin_amdgcn_s_setprio(1);                                               \
  _Pragma("unroll")                                                            \
  for (int ii = 0; ii < 4; ++ii)                                               \
    _Pragma("unroll")                                                          \
    for (int jj = 0; jj < 2; ++jj){                                            \
      acc[(MH)*4+ii][(NH)*2+jj] = __builtin_amdgcn_mfma_f32_16x16x32_f16(      \
          pa[ii][0], pb[jj][0], acc[(MH)*4+ii][(NH)*2+jj], 0, 0, 0);           \
      acc[(MH)*4+ii][(NH)*2+jj] = __builtin_amdgcn_mfma_f32_16x16x32_f16(      \
          pa[ii][1], pb[jj][1], acc[(MH)*4+ii][(NH)*2+jj], 0, 0, 0);           \
    }                                                                          \
  __builtin_amdgcn_s_setprio(0);

  // ---- prologue: tile0 staged+published into slot0; B(1) sets in flight ----
  glA(lds, 0, 0);  glA(lds, 0, 1);    // 4 entries
  SCH;
  issueB(0, 0, rbB0);                 // 8
  issueB(0, 1, rbB1);                 // 12
  SCH;
  WAIT_VM(4); SCH;                    // A(0) + B0(0) retired
  publishB(lds, 0, rbB0);
  WAIT_VM(0); SCH;                    // B1(0) retired
  publishB(lds, 1, rbB1);
  SCH;
  issueB(1, 0, rbB0);                 // 4
  issueB(1, 1, rbB1);                 // 8
  WAIT_LGKM0;
  SB; SCH;
  // entering T=0: outstanding [B0(1):4, B1(1):4] = 8  (invariant)

  for (int T = 0; T < NT; ++T){
    u16* sp  = lds + (size_t)(T & 1) * SLOT;
    u16* spn = lds + (size_t)((T + 1) & 1) * SLOT;
    const bool hasN  = (T + 1 < NT);
    const bool hasNN = (T + 2 < NT);

    // ---- phase A: quadrant (0,0); stage A0(T+1) ----
    READ_PA(sp, 0);
    READ_PB(sp, 0);
    if (hasN) glA(spn, T + 1, 0);
    WAIT_LGKM0; SCH;
    MMA(0, 0);

    // ---- phase B: quadrant (0,1); stage A1(T+1); publish B0(T+1); issue B0(T+2) ----
    READ_PB(sp, 1);
    if (hasN){
      glA(spn, T + 1, 1);
      SCH;
      WAIT_VM(8); SCH;                         // B0(T+1) retired
      publishB(spn, 0, rbB0);
      if (hasNN){ issueB(T + 2, 0, rbB0); SCH; }
    }
    WAIT_LGKM0; SCH;
    MMA(0, 1);

    // ---- phase C: quadrant (1,1); publish B1(T+1); issue B1(T+2) ----
    READ_PA(sp, 1);
    if (hasN){
      if (hasNN) { WAIT_VM(8); } else { WAIT_VM(4); }   // B1(T+1) retired
      SCH;
      publishB(spn, 1, rbB1);
      if (hasNN){ issueB(T + 2, 1, rbB1); SCH; }
    }
    WAIT_LGKM0; SCH;
    MMA(1, 1);

    // ---- phase D: quadrant (1,0); confirm A(T+1) landed; boundary barrier ----
    READ_PB(sp, 0);
    if (hasN){
      if (hasNN) { WAIT_VM(8); } else { WAIT_VM(0); }   // A(T+1) in LDS
      SCH;
    }
    WAIT_LGKM0; SCH;
    MMA(1, 0);
    SCH;
    SB;                                // ONE barrier per K-tile (slot swap)
  }

#undef READ_PA
#undef READ_PB
#undef MMA

  // ---- epilogue: row=(lane>>4)*4+reg (A idx), col=lane&15 (B idx) ----
  #pragma unroll
  for (int i = 0; i < 8; ++i){
    int rbase = m0 + wm * 128 + i * 16 + lg * 4;
    #pragma unroll
    for (int j = 0; j < 4; ++j){
      int gcol = n0 + wn * 64 + j * 16 + lr;
      if (gcol < NN){
        #pragma unroll
        for (int r = 0; r < 4; ++r){
          int grow = rbase + r;
          float v = (acc[i][j][r] + rowAdd[grow]) * alpha;
          C[(size_t)grow * NN + gcol] = v;
        }
      }
    }
  }
}

extern "C" void kernel_launch(void* const* d_in, const int* in_sizes, int n_in,
                              void* d_out, int out_size, void* d_ws, size_t ws_size,
                              hipStream_t stream){
  (void)in_sizes; (void)n_in; (void)out_size; (void)ws_size;
  const float* m    = (const float*)d_in[0];   // [512][2048]
  const float* tpl  = (const float*)d_in[1];   // [50000][2048]
  const float* Wmol = (const float*)d_in[2];   // [1024][2048]
  const float* bmol = (const float*)d_in[3];   // [1024]
  const float* Wtmp = (const float*)d_in[4];   // [1024][2048]
  const float* btmp = (const float*)d_in[5];   // [1024]
  float* out = (float*)d_out;                  // [512][50000]

  uint8_t* wp = (uint8_t*)d_ws;
  auto carve = [&](size_t bytes) -> void* {
    void* p = (void*)wp;
    wp += (bytes + 255) & ~(size_t)255;
    return p;
  };
  u16* m_bf   = (u16*)carve((size_t)BB_ * FP_ * 2);
  u16* wm_bf  = (u16*)carve((size_t)AD_ * FP_ * 2);
  u16* wtT_bf = (u16*)carve((size_t)FP_ * AD_ * 2);
  float* Xi   = (float*)carve((size_t)BB_ * AD_ * 4);
  u16* Xi_bf  = (u16*)carve((size_t)BB_ * AD_ * 2);
  u16* Y_hi   = (u16*)carve((size_t)BB_ * FP_ * 2);   // fp16 bits
  float* cvec = (float*)carve((size_t)BB_ * 4);

  // 1) single-bf16 conversions (W_temp also transposed to [FP][A])
  conv_bf_k<<<(BB_ * FP_ / 4 + 255) / 256, 256, 0, stream>>>(m, m_bf, BB_ * FP_);
  conv_bf_k<<<(AD_ * FP_ / 4 + 255) / 256, 256, 0, stream>>>(Wmol, wm_bf, AD_ * FP_);
  conv_bf_T_k<<<dim3(FP_ / 32, AD_ / 32), dim3(32, 8), 0, stream>>>(Wtmp, wtT_bf, AD_, FP_);

  // 2) Xi = m @ W_mol^T + b_mol   [512 x 1024], K=2048  (fp32 + bf16 out)
  gemm_s<64, 64, 2, 2, 1><<<dim3(BB_ / 64, AD_ / 64), 256, 0, stream>>>(
      m_bf, wm_bf, BB_, AD_, FP_, Xi, Xi_bf, bmol);

  // 3) c[b] = Xi[b,:] . b_temp
  dot_rows_k<<<BB_ / 4, 256, 0, stream>>>(Xi, btmp, cvec, AD_);

  // 4) Y = Xi @ W_temp   [512 x 2048], K=1024  -> fp16 single
  gemm_s<64, 64, 2, 2, 2><<<dim3(BB_ / 64, FP_ / 64), 256, 0, stream>>>(
      Xi_bf, wtT_bf, BB_, FP_, AD_, nullptr, Y_hi, nullptr);

  // 5) out = BETA * (Y @ templates^T + c)   [512 x 50000], K=2048
  //    400 blocks = 8 XCD x (2 M-tiles x 25 strip-slots); 8 masked. 1 block/CU.
  gemm_big<<<400, 512, 0, stream>>>(Y_hi, tpl, out, cvec, BETA_);
}